// Round 17
// baseline (117.562 us; speedup 1.0000x reference)
//
#include <hip/hip_runtime.h>
#include <hip/hip_bf16.h>

typedef __bf16 bf16x8 __attribute__((ext_vector_type(8)));
typedef float f32x4 __attribute__((ext_vector_type(4)));
typedef float f32x16 __attribute__((ext_vector_type(16)));
typedef unsigned short u16;
typedef u16 u16x8 __attribute__((ext_vector_type(8)));

__device__ __forceinline__ u16 f2bf(float f) {
  union { float f; unsigned u; } v; v.f = f;
  unsigned r = v.u + 0x7fffu + ((v.u >> 16) & 1u);
  return (u16)(r >> 16);
}
__device__ __forceinline__ float bf2f(u16 u) {
  union { unsigned u; float f; } v; v.u = (unsigned)u << 16; return v.f;
}
__device__ __forceinline__ unsigned cvtpk(float a, float b) {
  unsigned r;
  asm("v_cvt_pk_bf16_f32 %0, %1, %2" : "=v"(r) : "v"(a), "v"(b));
  return r;
}
__device__ __forceinline__ float exp2_(float x) {
  float r;
  asm("v_exp_f32 %0, %1" : "=v"(r) : "v"(x));
  return r;
}
__device__ __forceinline__ float sin2pi_(float x) {
  float r;
  asm("v_sin_f32 %0, %1" : "=v"(r) : "v"(x));
  return r;
}
__device__ __forceinline__ float cos2pi_(float x) {
  float r;
  asm("v_cos_f32 %0, %1" : "=v"(r) : "v"(x));
  return r;
}
// async global->LDS, 16B per lane, dest = wave-uniform base + lane*16
__device__ __forceinline__ void gload16(const void* g, void* l) {
  __builtin_amdgcn_global_load_lds(
      (__attribute__((address_space(1))) void*)(void*)g,
      (__attribute__((address_space(3))) void*)l, 16, 0, 0);
}

union U8 { bf16x8 v; unsigned u[4]; };

// ---------------- prep: x cast (blocks 0..2047) + both W transposes (2048..6143) ----------------
__global__ __launch_bounds__(256) void prep_k(const float* __restrict__ x,
                                              u16* __restrict__ xb,
                                              const float* __restrict__ Wq,
                                              const float* __restrict__ Wp,
                                              u16* __restrict__ Wqt,
                                              u16* __restrict__ Wpt) {
  __shared__ float tile[32][33];
  int bid = blockIdx.x;
  if (bid < 2048) {
    int id = bid * 256 + threadIdx.x;   // 524288 = M*C/8 exactly
    const float4* p = (const float4*)(x + (size_t)id * 8);
    float4 a = p[0], b = p[1];
    u16x8 o;
    o[0] = f2bf(a.x); o[1] = f2bf(a.y); o[2] = f2bf(a.z); o[3] = f2bf(a.w);
    o[4] = f2bf(b.x); o[5] = f2bf(b.y); o[6] = f2bf(b.z); o[7] = f2bf(b.w);
    *(u16x8*)(xb + (size_t)id * 8) = o;
    return;
  }
  int bb = bid - 2048;                  // 0..4095
  int bxr = bb >> 5;                    // 0..127
  int by = (bb & 31) * 32;
  const float* W; u16* Wt; int Cc, bx;
  if (bxr < 96) { W = Wq; Wt = Wqt; Cc = 3072; bx = bxr * 32; }
  else          { W = Wp; Wt = Wpt; Cc = 1024; bx = (bxr - 96) * 32; }
  const int R = 1024;
  int tx = threadIdx.x & 31, ty = threadIdx.x >> 5;
#pragma unroll
  for (int j = 0; j < 4; j++)
    tile[ty + j * 8][tx] = W[(size_t)(by + ty + j * 8) * Cc + bx + tx];
  __syncthreads();
#pragma unroll
  for (int j = 0; j < 4; j++)
    Wt[(size_t)(bx + ty + j * 8) * R + by + tx] = f2bf(tile[tx][ty + j * 8]);
}

// ---------------- GEMM: C[M][N] = A[M][K](bf16) * Bt[N][K](bf16) + bias ----------------
template <bool BF16OUT>
__global__ __launch_bounds__(256) void gemm_bt_k(const u16* __restrict__ A,
                                                 const u16* __restrict__ Bt,
                                                 const float* __restrict__ bias,
                                                 void* __restrict__ Cv,
                                                 int M, int N, int K) {
  __shared__ u16 As[128 * 64];
  __shared__ u16 Bs[128 * 64];
  int tid = threadIdx.x;
  int m0 = blockIdx.y * 128, n0 = blockIdx.x * 128;
  int wave = tid >> 6, lane = tid & 63;
  int wm = (wave & 1) * 64, wn = (wave >> 1) * 64;
  int lrow = lane & 15, lk = (lane >> 4) * 8;
  int rr = lane >> 3, cb = (lane & 7) * 16;

  f32x4 acc[4][4] = {};

  for (int k0 = 0; k0 < K; k0 += 64) {
#pragma unroll
    for (int i = 0; i < 4; i++) {
      int row = wave * 32 + i * 8 + rr;
      int cc = (cb ^ ((row & 7) << 4)) >> 1;
      gload16(A + (size_t)(m0 + row) * K + k0 + cc, &As[(wave * 32 + i * 8) * 64]);
      gload16(Bt + (size_t)(n0 + row) * K + k0 + cc, &Bs[(wave * 32 + i * 8) * 64]);
    }
    __syncthreads();
#pragma unroll
    for (int kk = 0; kk < 2; kk++) {
      bf16x8 af[4], bfr[4];
#pragma unroll
      for (int i = 0; i < 4; i++) {
        int arow = wm + i * 16 + lrow;
        int ab = (arow * 128 + (kk * 32 + lk) * 2) ^ ((arow & 7) << 4);
        af[i] = *(const bf16x8*)((const char*)As + ab);
        int brow = wn + i * 16 + lrow;
        int bb = (brow * 128 + (kk * 32 + lk) * 2) ^ ((brow & 7) << 4);
        bfr[i] = *(const bf16x8*)((const char*)Bs + bb);
      }
#pragma unroll
      for (int i = 0; i < 4; i++)
#pragma unroll
        for (int j = 0; j < 4; j++)
          acc[i][j] = __builtin_amdgcn_mfma_f32_16x16x32_bf16(af[i], bfr[j], acc[i][j], 0, 0, 0);
    }
    __syncthreads();
  }
  int rg = lane >> 4;
#pragma unroll
  for (int i = 0; i < 4; i++) {
#pragma unroll
    for (int j = 0; j < 4; j++) {
      int col = n0 + wn + j * 16 + lrow;
      float bz = bias ? bias[col] : 0.f;
#pragma unroll
      for (int r = 0; r < 4; r++) {
        int row = m0 + wm + i * 16 + rg * 4 + r;
        float val = acc[i][j][r] + bz;
        if constexpr (BF16OUT)
          ((u16*)Cv)[(size_t)row * N + col] = f2bf(val);
        else
          ((float*)Cv)[(size_t)row * N + col] = val;
      }
    }
  }
}

// ---------------- fused RoPE(q,k) + V transpose, fragment-major outputs ----------------
__global__ __launch_bounds__(256) void rope_pack_k(const u16* __restrict__ qkv,
                                                   u16* __restrict__ qf,
                                                   u16* __restrict__ kf,
                                                   u16* __restrict__ vf) {
  __shared__ u16 tl[64][72];
  int bh = blockIdx.x, tb = blockIdx.y;   // tb: 64-row t block
  int b = bh >> 4, h = bh & 15;
  int tid = threadIdx.x;
  int tloc = tid >> 2;                    // 0..63
  int a = tid & 3;                        // d-group: de in [16a, 16a+16)
  int tg = tb * 64 + tloc;
  const u16* rowp = qkv + ((size_t)(b * 2048 + tg)) * 3072 + h * 64 + 16 * a;
  u16x8 q0 = *(const u16x8*)(rowp);
  u16x8 q1 = *(const u16x8*)(rowp + 8);
  u16x8 k0 = *(const u16x8*)(rowp + 1024);
  u16x8 k1 = *(const u16x8*)(rowp + 1032);
  const float QS = 0.18033688011112042f;  // 0.125 * log2(e)
  const float C1 = -0.41524101186092029f; // -2*log2(10000)/64
  const float C2 = 0.15915494309189535f;  // 1/(2*pi)
  u16x8 qo0, qo1, ko0, ko1;
#pragma unroll
  for (int j = 0; j < 8; j++) {
    int i = 8 * a + j;
    float fr = (float)tg * (exp2f((float)i * C1) * C2);
    fr = fr - floorf(fr);
    float sv = sin2pi_(fr), cv = cos2pi_(fr);
    float qx, qy, kx, ky;
    if (j < 4) {
      qx = bf2f(q0[2 * j]); qy = bf2f(q0[2 * j + 1]);
      kx = bf2f(k0[2 * j]); ky = bf2f(k0[2 * j + 1]);
    } else {
      qx = bf2f(q1[2 * j - 8]); qy = bf2f(q1[2 * j - 7]);
      kx = bf2f(k1[2 * j - 8]); ky = bf2f(k1[2 * j - 7]);
    }
    u16 qre = f2bf((qx * cv - qy * sv) * QS), qro = f2bf((qx * sv + qy * cv) * QS);
    u16 kre = f2bf(kx * cv - ky * sv),        kro = f2bf(kx * sv + ky * cv);
    if (j < 4) { qo0[2 * j] = qre; qo0[2 * j + 1] = qro; ko0[2 * j] = kre; ko0[2 * j + 1] = kro; }
    else       { qo1[2 * j - 8] = qre; qo1[2 * j - 7] = qro; ko1[2 * j - 8] = kre; ko1[2 * j - 7] = kro; }
  }
  size_t qbase = ((size_t)bh * 64 + (tg >> 5)) * 2048 + a * 512 + (tg & 31) * 8;
  *(u16x8*)(qf + qbase) = qo0;
  *(u16x8*)(qf + qbase + 256) = qo1;
  size_t kbase = (((size_t)bh * 32 + (tg >> 6)) * 2 + ((tg >> 5) & 1)) * 2048 + a * 512 + (tg & 31) * 8;
  *(u16x8*)(kf + kbase) = ko0;
  *(u16x8*)(kf + kbase + 256) = ko1;
  // ---- V transpose through LDS ----
#pragma unroll
  for (int rep = 0; rep < 2; rep++) {
    int tr = rep * 32 + (tid >> 3);
    int dc = (tid & 7) * 8;
    u16x8 v = *(const u16x8*)(qkv + ((size_t)(b * 2048 + tb * 64 + tr)) * 3072 + 2048 + h * 64 + dc);
    *(u16x8*)&tl[tr][dc] = v;
  }
  __syncthreads();
  u16* dst = vf + ((size_t)bh * 32 + tb) * 4096;
#pragma unroll
  for (int rep = 0; rep < 2; rep++) {
    int c = rep * 256 + tid;
    int dh = c >> 8, s = (c >> 6) & 3, l = c & 63;
    int hi = l >> 5, ql = l & 31;
    u16x8 o;
#pragma unroll
    for (int j = 0; j < 8; j++) o[j] = tl[s * 16 + hi * 8 + j][dh * 32 + ql];
    *(u16x8*)(dst + (size_t)c * 8) = o;
  }
}

// ---------------- flash attention v14: v13 + s_setprio around MFMA clusters ----------------
#define KPREF(K0, K1, IT)                                                         \
  do {                                                                            \
    const u16* kb_ = KfP + (size_t)(IT) * 4096 + ln8;                             \
    _Pragma("unroll") for (int d_ = 0; d_ < 4; d_++) {                            \
      K0[d_] = *(const bf16x8*)(kb_ + d_ * 512);                                  \
      K1[d_] = *(const bf16x8*)(kb_ + 2048 + d_ * 512);                           \
    }                                                                             \
  } while (0)

#define QKC(SA, SB, K0, K1)                                                       \
  do {                                                                            \
    SA = (f32x16){};                                                              \
    SB = (f32x16){};                                                              \
    __builtin_amdgcn_s_setprio(1);                                                \
    _Pragma("unroll") for (int d_ = 0; d_ < 4; d_++) {                            \
      SA = __builtin_amdgcn_mfma_f32_32x32x16_bf16(K0[d_], qfr[d_], SA, 0, 0, 0); \
      SB = __builtin_amdgcn_mfma_f32_32x32x16_bf16(K1[d_], qfr[d_], SB, 0, 0, 0); \
    }                                                                             \
    __builtin_amdgcn_s_setprio(0);                                                \
  } while (0)

#define VLOADM(IT)                                                                \
  do {                                                                            \
    const u16* vb_ = VfP + (size_t)(IT) * 4096 + ln8;                             \
    _Pragma("unroll") for (int s_ = 0; s_ < 4; s_++) {                            \
      vv0[s_] = *(const bf16x8*)(vb_ + s_ * 512);                                 \
      vv1[s_] = *(const bf16x8*)(vb_ + 2048 + s_ * 512);                          \
    }                                                                             \
  } while (0)

#define SMPV(SA, SB, IT, MASKF)                                                   \
  do {                                                                            \
    if (MASKF) {                                                                  \
      int kv0_ = (IT) * 64;                                                       \
      _Pragma("unroll") for (int r_ = 0; r_ < 16; r_++) {                         \
        int ro_ = (r_ & 3) + 8 * (r_ >> 2) + 4 * hi;                              \
        if (kv0_ + ro_ > qg) SA[r_] = -3e38f;                                     \
        if (kv0_ + 32 + ro_ > qg) SB[r_] = -3e38f;                                \
      }                                                                           \
    }                                                                             \
    _Pragma("unroll") for (int r_ = 0; r_ < 16; r_++) {                           \
      SA[r_] = exp2_(SA[r_]);                                                     \
      SB[r_] = exp2_(SB[r_]);                                                     \
    }                                                                             \
    unsigned w0_ = cvtpk(SA[0], SA[1]),   w1_ = cvtpk(SA[2], SA[3]);              \
    unsigned w2_ = cvtpk(SA[4], SA[5]),   w3_ = cvtpk(SA[6], SA[7]);              \
    unsigned w4_ = cvtpk(SA[8], SA[9]),   w5_ = cvtpk(SA[10], SA[11]);            \
    unsigned w6_ = cvtpk(SA[12], SA[13]), w7_ = cvtpk(SA[14], SA[15]);            \
    unsigned y0_ = cvtpk(SB[0], SB[1]),   y1_ = cvtpk(SB[2], SB[3]);              \
    unsigned y2_ = cvtpk(SB[4], SB[5]),   y3_ = cvtpk(SB[6], SB[7]);              \
    unsigned y4_ = cvtpk(SB[8], SB[9]),   y5_ = cvtpk(SB[10], SB[11]);            \
    unsigned y6_ = cvtpk(SB[12], SB[13]), y7_ = cvtpk(SB[14], SB[15]);            \
    asm("v_permlane32_swap_b32 %0, %1" : "+v"(w0_), "+v"(w2_));                   \
    asm("v_permlane32_swap_b32 %0, %1" : "+v"(w1_), "+v"(w3_));                   \
    asm("v_permlane32_swap_b32 %0, %1" : "+v"(w4_), "+v"(w6_));                   \
    asm("v_permlane32_swap_b32 %0, %1" : "+v"(w5_), "+v"(w7_));                   \
    asm("v_permlane32_swap_b32 %0, %1" : "+v"(y0_), "+v"(y2_));                   \
    asm("v_permlane32_swap_b32 %0, %1" : "+v"(y1_), "+v"(y3_));                   \
    asm("v_permlane32_swap_b32 %0, %1" : "+v"(y4_), "+v"(y6_));                   \
    asm("v_permlane32_swap_b32 %0, %1" : "+v"(y5_), "+v"(y7_));                   \
    U8 pf0_, pf1_, pf2_, pf3_;                                                    \
    pf0_.u[0] = w0_; pf0_.u[1] = w1_; pf0_.u[2] = w2_; pf0_.u[3] = w3_;           \
    pf1_.u[0] = w4_; pf1_.u[1] = w5_; pf1_.u[2] = w6_; pf1_.u[3] = w7_;           \
    pf2_.u[0] = y0_; pf2_.u[1] = y1_; pf2_.u[2] = y2_; pf2_.u[3] = y3_;           \
    pf3_.u[0] = y4_; pf3_.u[1] = y5_; pf3_.u[2] = y6_; pf3_.u[3] = y7_;           \
    __builtin_amdgcn_s_setprio(1);                                                \
    o0 = __builtin_amdgcn_mfma_f32_32x32x16_bf16(vv0[0], pf0_.v, o0, 0, 0, 0);    \
    o1 = __builtin_amdgcn_mfma_f32_32x32x16_bf16(vv1[0], pf0_.v, o1, 0, 0, 0);    \
    o0 = __builtin_amdgcn_mfma_f32_32x32x16_bf16(vv0[1], pf1_.v, o0, 0, 0, 0);    \
    o1 = __builtin_amdgcn_mfma_f32_32x32x16_bf16(vv1[1], pf1_.v, o1, 0, 0, 0);    \
    o0 = __builtin_amdgcn_mfma_f32_32x32x16_bf16(vv0[2], pf2_.v, o0, 0, 0, 0);    \
    o1 = __builtin_amdgcn_mfma_f32_32x32x16_bf16(vv1[2], pf2_.v, o1, 0, 0, 0);    \
    o0 = __builtin_amdgcn_mfma_f32_32x32x16_bf16(vv0[3], pf3_.v, o0, 0, 0, 0);    \
    o1 = __builtin_amdgcn_mfma_f32_32x32x16_bf16(vv1[3], pf3_.v, o1, 0, 0, 0);    \
    ls = __builtin_amdgcn_mfma_f32_32x32x16_bf16(onesf.v, pf0_.v, ls, 0, 0, 0);   \
    ls = __builtin_amdgcn_mfma_f32_32x32x16_bf16(onesf.v, pf1_.v, ls, 0, 0, 0);   \
    ls = __builtin_amdgcn_mfma_f32_32x32x16_bf16(onesf.v, pf2_.v, ls, 0, 0, 0);   \
    ls = __builtin_amdgcn_mfma_f32_32x32x16_bf16(onesf.v, pf3_.v, ls, 0, 0, 0);   \
    __builtin_amdgcn_s_setprio(0);                                                \
  } while (0)

__global__ __launch_bounds__(64) void attn_k(const u16* __restrict__ Qf,
                                             const u16* __restrict__ Kf,
                                             const u16* __restrict__ Vf,
                                             u16* __restrict__ sc,
                                             u16* __restrict__ pO,
                                             float* __restrict__ pL) {
  const int T = 2048;
  int blk = blockIdx.x;
  int bh = (blk & 7) * 4 + ((blk >> 3) & 3);  // XCD-pinned bh groups
  int c = blk >> 5;                            // 0..79, longest-first
  int qt, slot, nslots;
  if (c < 32) { qt = 63 - (c >> 1); slot = c & 1; nslots = 2; }  // qt 48..63
  else        { qt = 79 - c;        slot = 0;     nslots = 1; }  // qt 0..47
  int nTot = (qt >> 1) + 1;                    // 64-row KV bodies
  int it0 = (nTot * slot) / nslots;
  int itEnd = (nTot * (slot + 1)) / nslots;
  int lane = threadIdx.x & 63;
  int ql = lane & 31, hi = lane >> 5;
  int ln8 = lane * 8;
  int qg = qt * 32 + ql;
  const u16* QfP = Qf + (size_t)bh * 64 * 2048;
  const u16* KfP = Kf + (size_t)bh * 32 * 4096;
  const u16* VfP = Vf + (size_t)bh * 32 * 4096;
  int b = bh >> 4, h = bh & 15;

  U8 onesf;
#pragma unroll
  for (int j = 0; j < 4; j++) onesf.u[j] = 0x3F803F80u;

  bf16x8 qfr[4];
#pragma unroll
  for (int ds = 0; ds < 4; ds++)
    qfr[ds] = *(const bf16x8*)(QfP + (size_t)qt * 2048 + ds * 512 + ln8);

  f32x16 o0 = {}, o1 = {}, ls = {};
  bf16x8 Ka0[4], Ka1[4], Kb0[4], Kb1[4], vv0[4], vv1[4];
  f32x16 sA0, sA1, sB0, sB1;

  int t = it0;
  KPREF(Ka0, Ka1, t);
  QKC(sA0, sA1, Ka0, Ka1);
  if (t + 1 < itEnd) KPREF(Kb0, Kb1, t + 1);

  for (;;) {
    bool last = (t == itEnd - 1);
    VLOADM(t);
    if (t + 2 < itEnd) KPREF(Ka0, Ka1, t + 2);
    if (!last) QKC(sB0, sB1, Kb0, Kb1);
    SMPV(sA0, sA1, t, t == nTot - 1);
    if (last) break;
    ++t;
    last = (t == itEnd - 1);
    VLOADM(t);
    if (t + 2 < itEnd) KPREF(Kb0, Kb1, t + 2);
    if (!last) QKC(sA0, sA1, Ka0, Ka1);
    SMPV(sB0, sB1, t, t == nTot - 1);
    if (last) break;
    ++t;
  }

  if (nslots == 1) {
    float inv = 1.f / ls[0];
    u16* orow = sc + ((size_t)(b * T + qg)) * 1024 + h * 64;
#pragma unroll
    for (int j = 0; j < 4; j++) {
      ushort4 o;
      o.x = f2bf(o0[4 * j + 0] * inv); o.y = f2bf(o0[4 * j + 1] * inv);
      o.z = f2bf(o0[4 * j + 2] * inv); o.w = f2bf(o0[4 * j + 3] * inv);
      *(ushort4*)(orow + 8 * j + 4 * hi) = o;
      ushort4 q2;
      q2.x = f2bf(o1[4 * j + 0] * inv); q2.y = f2bf(o1[4 * j + 1] * inv);
      q2.z = f2bf(o1[4 * j + 2] * inv); q2.w = f2bf(o1[4 * j + 3] * inv);
      *(ushort4*)(orow + 32 + 8 * j + 4 * hi) = q2;
    }
  } else {
    u16* orow = pO + (size_t)slot * 4194304 + ((size_t)(b * T + qg)) * 1024 + h * 64;
#pragma unroll
    for (int j = 0; j < 4; j++) {
      ushort4 o;
      o.x = f2bf(o0[4 * j + 0]); o.y = f2bf(o0[4 * j + 1]);
      o.z = f2bf(o0[4 * j + 2]); o.w = f2bf(o0[4 * j + 3]);
      *(ushort4*)(orow + 8 * j + 4 * hi) = o;
      ushort4 q2;
      q2.x = f2bf(o1[4 * j + 0]); q2.y = f2bf(o1[4 * j + 1]);
      q2.z = f2bf(o1[4 * j + 2]); q2.w = f2bf(o1[4 * j + 3]);
      *(ushort4*)(orow + 32 + 8 * j + 4 * hi) = q2;
    }
    if (hi == 0) pL[slot * 65536 + bh * 2048 + qg] = ls[0];
  }
}

// ---------------- merge partials (rows t >= 1536 only): sc = (O0+O1)/(l0+l1) ----------------
__global__ __launch_bounds__(256) void mrg_k(const u16* __restrict__ pO,
                                             const float* __restrict__ pL,
                                             u16* __restrict__ sc) {
  int id = blockIdx.x * 256 + threadIdx.x;   // 131072 = 2b x 512t x 128 col8
  int col8 = id & 127;
  int rp = id >> 7;                           // 0..1023
  int b = rp >> 9;
  int t = 1536 + (rp & 511);
  int h = col8 >> 3;
  int bh = b * 16 + h;
  size_t idx8 = ((size_t)(b * 2048 + t) * 128 + col8);
  float l0 = pL[bh * 2048 + t];
  float l1 = pL[65536 + bh * 2048 + t];
  u16x8 v0 = *(const u16x8*)(pO + idx8 * 8);
  u16x8 v1 = *(const u16x8*)(pO + 4194304 + idx8 * 8);
  float inv = 1.f / (l0 + l1);
  u16x8 o;
#pragma unroll
  for (int j = 0; j < 8; j++) o[j] = f2bf((bf2f(v0[j]) + bf2f(v1[j])) * inv);
  *(u16x8*)(sc + idx8 * 8) = o;
}

extern "C" void kernel_launch(void* const* d_in, const int* in_sizes, int n_in,
                              void* d_out, int out_size, void* d_ws, size_t ws_size,
                              hipStream_t stream) {
  const float* x      = (const float*)d_in[0];
  const float* W_qkv  = (const float*)d_in[1];
  const float* b_qkv  = (const float*)d_in[2];
  const float* W_proj = (const float*)d_in[3];
  const float* b_proj = (const float*)d_in[4];
  float* out = (float*)d_out;

  const int B = 2, T = 2048, C = 1024;
  const int M = B * T;  // 4096

  // ws map (MB). Partials overlay xb/wqkvt (dead during attn):
  // [0,2) wprojt | [2,10) xb | [10,16) wqkvt | [16,40) qkvb
  // pO = [2,18) (2 x 8MB slots) | pL = [34,35)
  // [40,48) qfb | [48,56) kfb | [56,64) vfb | [64,72) sc
  char* ws = (char*)d_ws;
  u16* wprojt = (u16*)(ws);
  u16* xb     = (u16*)(ws + (2ull << 20));
  u16* wqkvt  = (u16*)(ws + (10ull << 20));
  u16* qkvb   = (u16*)(ws + (16ull << 20));
  u16* pO     = (u16*)(ws + (2ull << 20));
  float* pL   = (float*)(ws + (34ull << 20));
  u16* qfb    = (u16*)(ws + (40ull << 20));
  u16* kfb    = (u16*)(ws + (48ull << 20));
  u16* vfb    = (u16*)(ws + (56ull << 20));
  u16* sc     = (u16*)(ws + (64ull << 20));

  prep_k<<<6144, 256, 0, stream>>>(x, xb, W_qkv, W_proj, wqkvt, wprojt);
  gemm_bt_k<true><<<dim3(3 * C / 128, M / 128), 256, 0, stream>>>(xb, wqkvt, b_qkv, qkvb, M, 3 * C, C);
  rope_pack_k<<<dim3(B * 16, T / 64), 256, 0, stream>>>(qkvb, qfb, kfb, vfb);
  attn_k<<<2560, 64, 0, stream>>>(qfb, kfb, vfb, sc, pO, pL);
  mrg_k<<<512, 256, 0, stream>>>(pO, pL, sc);
  gemm_bt_k<false><<<dim3(C / 128, M / 128), 256, 0, stream>>>(sc, wprojt, b_proj, out, M, C, C);
}

// Round 18
// 114.399 us; speedup vs baseline: 1.0276x; 1.0276x over previous
//
#include <hip/hip_runtime.h>
#include <hip/hip_bf16.h>

typedef __bf16 bf16x8 __attribute__((ext_vector_type(8)));
typedef float f32x4 __attribute__((ext_vector_type(4)));
typedef float f32x16 __attribute__((ext_vector_type(16)));
typedef unsigned short u16;
typedef u16 u16x8 __attribute__((ext_vector_type(8)));

__device__ __forceinline__ u16 f2bf(float f) {
  union { float f; unsigned u; } v; v.f = f;
  unsigned r = v.u + 0x7fffu + ((v.u >> 16) & 1u);
  return (u16)(r >> 16);
}
__device__ __forceinline__ float bf2f(u16 u) {
  union { unsigned u; float f; } v; v.u = (unsigned)u << 16; return v.f;
}
__device__ __forceinline__ unsigned cvtpk(float a, float b) {
  unsigned r;
  asm("v_cvt_pk_bf16_f32 %0, %1, %2" : "=v"(r) : "v"(a), "v"(b));
  return r;
}
__device__ __forceinline__ float exp2_(float x) {
  float r;
  asm("v_exp_f32 %0, %1" : "=v"(r) : "v"(x));
  return r;
}
__device__ __forceinline__ float sin2pi_(float x) {
  float r;
  asm("v_sin_f32 %0, %1" : "=v"(r) : "v"(x));
  return r;
}
__device__ __forceinline__ float cos2pi_(float x) {
  float r;
  asm("v_cos_f32 %0, %1" : "=v"(r) : "v"(x));
  return r;
}
// async global->LDS, 16B per lane, dest = wave-uniform base + lane*16
__device__ __forceinline__ void gload16(const void* g, void* l) {
  __builtin_amdgcn_global_load_lds(
      (__attribute__((address_space(1))) void*)(void*)g,
      (__attribute__((address_space(3))) void*)l, 16, 0, 0);
}

union U8 { bf16x8 v; unsigned u[4]; };

// ---------------- prep: x cast (blocks 0..2047) + both W transposes (2048..6143) ----------------
__global__ __launch_bounds__(256) void prep_k(const float* __restrict__ x,
                                              u16* __restrict__ xb,
                                              const float* __restrict__ Wq,
                                              const float* __restrict__ Wp,
                                              u16* __restrict__ Wqt,
                                              u16* __restrict__ Wpt) {
  __shared__ float tile[32][33];
  int bid = blockIdx.x;
  if (bid < 2048) {
    int id = bid * 256 + threadIdx.x;   // 524288 = M*C/8 exactly
    const float4* p = (const float4*)(x + (size_t)id * 8);
    float4 a = p[0], b = p[1];
    u16x8 o;
    o[0] = f2bf(a.x); o[1] = f2bf(a.y); o[2] = f2bf(a.z); o[3] = f2bf(a.w);
    o[4] = f2bf(b.x); o[5] = f2bf(b.y); o[6] = f2bf(b.z); o[7] = f2bf(b.w);
    *(u16x8*)(xb + (size_t)id * 8) = o;
    return;
  }
  int bb = bid - 2048;                  // 0..4095
  int bxr = bb >> 5;                    // 0..127
  int by = (bb & 31) * 32;
  const float* W; u16* Wt; int Cc, bx;
  if (bxr < 96) { W = Wq; Wt = Wqt; Cc = 3072; bx = bxr * 32; }
  else          { W = Wp; Wt = Wpt; Cc = 1024; bx = (bxr - 96) * 32; }
  const int R = 1024;
  int tx = threadIdx.x & 31, ty = threadIdx.x >> 5;
#pragma unroll
  for (int j = 0; j < 4; j++)
    tile[ty + j * 8][tx] = W[(size_t)(by + ty + j * 8) * Cc + bx + tx];
  __syncthreads();
#pragma unroll
  for (int j = 0; j < 4; j++)
    Wt[(size_t)(bx + ty + j * 8) * R + by + tx] = f2bf(tile[tx][ty + j * 8]);
}

// ---------------- GEMM: C[M][N] = A[M][K](bf16) * Bt[N][K](bf16) + bias ----------------
template <bool BF16OUT>
__global__ __launch_bounds__(256) void gemm_bt_k(const u16* __restrict__ A,
                                                 const u16* __restrict__ Bt,
                                                 const float* __restrict__ bias,
                                                 void* __restrict__ Cv,
                                                 int M, int N, int K) {
  __shared__ u16 As[128 * 64];
  __shared__ u16 Bs[128 * 64];
  int tid = threadIdx.x;
  int m0 = blockIdx.y * 128, n0 = blockIdx.x * 128;
  int wave = tid >> 6, lane = tid & 63;
  int wm = (wave & 1) * 64, wn = (wave >> 1) * 64;
  int lrow = lane & 15, lk = (lane >> 4) * 8;
  int rr = lane >> 3, cb = (lane & 7) * 16;

  f32x4 acc[4][4] = {};

  for (int k0 = 0; k0 < K; k0 += 64) {
#pragma unroll
    for (int i = 0; i < 4; i++) {
      int row = wave * 32 + i * 8 + rr;
      int cc = (cb ^ ((row & 7) << 4)) >> 1;
      gload16(A + (size_t)(m0 + row) * K + k0 + cc, &As[(wave * 32 + i * 8) * 64]);
      gload16(Bt + (size_t)(n0 + row) * K + k0 + cc, &Bs[(wave * 32 + i * 8) * 64]);
    }
    __syncthreads();
#pragma unroll
    for (int kk = 0; kk < 2; kk++) {
      bf16x8 af[4], bfr[4];
#pragma unroll
      for (int i = 0; i < 4; i++) {
        int arow = wm + i * 16 + lrow;
        int ab = (arow * 128 + (kk * 32 + lk) * 2) ^ ((arow & 7) << 4);
        af[i] = *(const bf16x8*)((const char*)As + ab);
        int brow = wn + i * 16 + lrow;
        int bb = (brow * 128 + (kk * 32 + lk) * 2) ^ ((brow & 7) << 4);
        bfr[i] = *(const bf16x8*)((const char*)Bs + bb);
      }
#pragma unroll
      for (int i = 0; i < 4; i++)
#pragma unroll
        for (int j = 0; j < 4; j++)
          acc[i][j] = __builtin_amdgcn_mfma_f32_16x16x32_bf16(af[i], bfr[j], acc[i][j], 0, 0, 0);
    }
    __syncthreads();
  }
  int rg = lane >> 4;
#pragma unroll
  for (int i = 0; i < 4; i++) {
#pragma unroll
    for (int j = 0; j < 4; j++) {
      int col = n0 + wn + j * 16 + lrow;
      float bz = bias ? bias[col] : 0.f;
#pragma unroll
      for (int r = 0; r < 4; r++) {
        int row = m0 + wm + i * 16 + rg * 4 + r;
        float val = acc[i][j][r] + bz;
        if constexpr (BF16OUT)
          ((u16*)Cv)[(size_t)row * N + col] = f2bf(val);
        else
          ((float*)Cv)[(size_t)row * N + col] = val;
      }
    }
  }
}

// ---------------- fused RoPE(q,k) + V transpose, fragment-major outputs ----------------
__global__ __launch_bounds__(256) void rope_pack_k(const u16* __restrict__ qkv,
                                                   u16* __restrict__ qf,
                                                   u16* __restrict__ kf,
                                                   u16* __restrict__ vf) {
  __shared__ u16 tl[64][72];
  int bh = blockIdx.x, tb = blockIdx.y;   // tb: 64-row t block
  int b = bh >> 4, h = bh & 15;
  int tid = threadIdx.x;
  int tloc = tid >> 2;                    // 0..63
  int a = tid & 3;                        // d-group: de in [16a, 16a+16)
  int tg = tb * 64 + tloc;
  const u16* rowp = qkv + ((size_t)(b * 2048 + tg)) * 3072 + h * 64 + 16 * a;
  u16x8 q0 = *(const u16x8*)(rowp);
  u16x8 q1 = *(const u16x8*)(rowp + 8);
  u16x8 k0 = *(const u16x8*)(rowp + 1024);
  u16x8 k1 = *(const u16x8*)(rowp + 1032);
  const float QS = 0.18033688011112042f;  // 0.125 * log2(e)
  const float C1 = -0.41524101186092029f; // -2*log2(10000)/64
  const float C2 = 0.15915494309189535f;  // 1/(2*pi)
  u16x8 qo0, qo1, ko0, ko1;
#pragma unroll
  for (int j = 0; j < 8; j++) {
    int i = 8 * a + j;
    float fr = (float)tg * (exp2f((float)i * C1) * C2);
    fr = fr - floorf(fr);
    float sv = sin2pi_(fr), cv = cos2pi_(fr);
    float qx, qy, kx, ky;
    if (j < 4) {
      qx = bf2f(q0[2 * j]); qy = bf2f(q0[2 * j + 1]);
      kx = bf2f(k0[2 * j]); ky = bf2f(k0[2 * j + 1]);
    } else {
      qx = bf2f(q1[2 * j - 8]); qy = bf2f(q1[2 * j - 7]);
      kx = bf2f(k1[2 * j - 8]); ky = bf2f(k1[2 * j - 7]);
    }
    u16 qre = f2bf((qx * cv - qy * sv) * QS), qro = f2bf((qx * sv + qy * cv) * QS);
    u16 kre = f2bf(kx * cv - ky * sv),        kro = f2bf(kx * sv + ky * cv);
    if (j < 4) { qo0[2 * j] = qre; qo0[2 * j + 1] = qro; ko0[2 * j] = kre; ko0[2 * j + 1] = kro; }
    else       { qo1[2 * j - 8] = qre; qo1[2 * j - 7] = qro; ko1[2 * j - 8] = kre; ko1[2 * j - 7] = kro; }
  }
  size_t qbase = ((size_t)bh * 64 + (tg >> 5)) * 2048 + a * 512 + (tg & 31) * 8;
  *(u16x8*)(qf + qbase) = qo0;
  *(u16x8*)(qf + qbase + 256) = qo1;
  size_t kbase = (((size_t)bh * 32 + (tg >> 6)) * 2 + ((tg >> 5) & 1)) * 2048 + a * 512 + (tg & 31) * 8;
  *(u16x8*)(kf + kbase) = ko0;
  *(u16x8*)(kf + kbase + 256) = ko1;
  // ---- V transpose through LDS ----
#pragma unroll
  for (int rep = 0; rep < 2; rep++) {
    int tr = rep * 32 + (tid >> 3);
    int dc = (tid & 7) * 8;
    u16x8 v = *(const u16x8*)(qkv + ((size_t)(b * 2048 + tb * 64 + tr)) * 3072 + 2048 + h * 64 + dc);
    *(u16x8*)&tl[tr][dc] = v;
  }
  __syncthreads();
  u16* dst = vf + ((size_t)bh * 32 + tb) * 4096;
#pragma unroll
  for (int rep = 0; rep < 2; rep++) {
    int c = rep * 256 + tid;
    int dh = c >> 8, s = (c >> 6) & 3, l = c & 63;
    int hi = l >> 5, ql = l & 31;
    u16x8 o;
#pragma unroll
    for (int j = 0; j < 8; j++) o[j] = tl[s * 16 + hi * 8 + j][dh * 32 + ql];
    *(u16x8*)(dst + (size_t)c * 8) = o;
  }
}

// ---------------- flash attention v13: v9 pipeline + quarter-chunking ----------------
#define KPREF(K0, K1, IT)                                                         \
  do {                                                                            \
    const u16* kb_ = KfP + (size_t)(IT) * 4096 + ln8;                             \
    _Pragma("unroll") for (int d_ = 0; d_ < 4; d_++) {                            \
      K0[d_] = *(const bf16x8*)(kb_ + d_ * 512);                                  \
      K1[d_] = *(const bf16x8*)(kb_ + 2048 + d_ * 512);                           \
    }                                                                             \
  } while (0)

#define QKC(SA, SB, K0, K1)                                                       \
  do {                                                                            \
    SA = (f32x16){};                                                              \
    SB = (f32x16){};                                                              \
    _Pragma("unroll") for (int d_ = 0; d_ < 4; d_++) {                            \
      SA = __builtin_amdgcn_mfma_f32_32x32x16_bf16(K0[d_], qfr[d_], SA, 0, 0, 0); \
      SB = __builtin_amdgcn_mfma_f32_32x32x16_bf16(K1[d_], qfr[d_], SB, 0, 0, 0); \
    }                                                                             \
  } while (0)

#define VLOADM(IT)                                                                \
  do {                                                                            \
    const u16* vb_ = VfP + (size_t)(IT) * 4096 + ln8;                             \
    _Pragma("unroll") for (int s_ = 0; s_ < 4; s_++) {                            \
      vv0[s_] = *(const bf16x8*)(vb_ + s_ * 512);                                 \
      vv1[s_] = *(const bf16x8*)(vb_ + 2048 + s_ * 512);                          \
    }                                                                             \
  } while (0)

#define SMPV(SA, SB, IT, MASKF)                                                   \
  do {                                                                            \
    if (MASKF) {                                                                  \
      int kv0_ = (IT) * 64;                                                       \
      _Pragma("unroll") for (int r_ = 0; r_ < 16; r_++) {                         \
        int ro_ = (r_ & 3) + 8 * (r_ >> 2) + 4 * hi;                              \
        if (kv0_ + ro_ > qg) SA[r_] = -3e38f;                                     \
        if (kv0_ + 32 + ro_ > qg) SB[r_] = -3e38f;                                \
      }                                                                           \
    }                                                                             \
    _Pragma("unroll") for (int r_ = 0; r_ < 16; r_++) {                           \
      SA[r_] = exp2_(SA[r_]);                                                     \
      SB[r_] = exp2_(SB[r_]);                                                     \
    }                                                                             \
    unsigned w0_ = cvtpk(SA[0], SA[1]),   w1_ = cvtpk(SA[2], SA[3]);              \
    unsigned w2_ = cvtpk(SA[4], SA[5]),   w3_ = cvtpk(SA[6], SA[7]);              \
    unsigned w4_ = cvtpk(SA[8], SA[9]),   w5_ = cvtpk(SA[10], SA[11]);            \
    unsigned w6_ = cvtpk(SA[12], SA[13]), w7_ = cvtpk(SA[14], SA[15]);            \
    unsigned y0_ = cvtpk(SB[0], SB[1]),   y1_ = cvtpk(SB[2], SB[3]);              \
    unsigned y2_ = cvtpk(SB[4], SB[5]),   y3_ = cvtpk(SB[6], SB[7]);              \
    unsigned y4_ = cvtpk(SB[8], SB[9]),   y5_ = cvtpk(SB[10], SB[11]);            \
    unsigned y6_ = cvtpk(SB[12], SB[13]), y7_ = cvtpk(SB[14], SB[15]);            \
    asm("v_permlane32_swap_b32 %0, %1" : "+v"(w0_), "+v"(w2_));                   \
    asm("v_permlane32_swap_b32 %0, %1" : "+v"(w1_), "+v"(w3_));                   \
    asm("v_permlane32_swap_b32 %0, %1" : "+v"(w4_), "+v"(w6_));                   \
    asm("v_permlane32_swap_b32 %0, %1" : "+v"(w5_), "+v"(w7_));                   \
    asm("v_permlane32_swap_b32 %0, %1" : "+v"(y0_), "+v"(y2_));                   \
    asm("v_permlane32_swap_b32 %0, %1" : "+v"(y1_), "+v"(y3_));                   \
    asm("v_permlane32_swap_b32 %0, %1" : "+v"(y4_), "+v"(y6_));                   \
    asm("v_permlane32_swap_b32 %0, %1" : "+v"(y5_), "+v"(y7_));                   \
    U8 pf0_, pf1_, pf2_, pf3_;                                                    \
    pf0_.u[0] = w0_; pf0_.u[1] = w1_; pf0_.u[2] = w2_; pf0_.u[3] = w3_;           \
    pf1_.u[0] = w4_; pf1_.u[1] = w5_; pf1_.u[2] = w6_; pf1_.u[3] = w7_;           \
    pf2_.u[0] = y0_; pf2_.u[1] = y1_; pf2_.u[2] = y2_; pf2_.u[3] = y3_;           \
    pf3_.u[0] = y4_; pf3_.u[1] = y5_; pf3_.u[2] = y6_; pf3_.u[3] = y7_;           \
    o0 = __builtin_amdgcn_mfma_f32_32x32x16_bf16(vv0[0], pf0_.v, o0, 0, 0, 0);    \
    o1 = __builtin_amdgcn_mfma_f32_32x32x16_bf16(vv1[0], pf0_.v, o1, 0, 0, 0);    \
    o0 = __builtin_amdgcn_mfma_f32_32x32x16_bf16(vv0[1], pf1_.v, o0, 0, 0, 0);    \
    o1 = __builtin_amdgcn_mfma_f32_32x32x16_bf16(vv1[1], pf1_.v, o1, 0, 0, 0);    \
    o0 = __builtin_amdgcn_mfma_f32_32x32x16_bf16(vv0[2], pf2_.v, o0, 0, 0, 0);    \
    o1 = __builtin_amdgcn_mfma_f32_32x32x16_bf16(vv1[2], pf2_.v, o1, 0, 0, 0);    \
    o0 = __builtin_amdgcn_mfma_f32_32x32x16_bf16(vv0[3], pf3_.v, o0, 0, 0, 0);    \
    o1 = __builtin_amdgcn_mfma_f32_32x32x16_bf16(vv1[3], pf3_.v, o1, 0, 0, 0);    \
    ls = __builtin_amdgcn_mfma_f32_32x32x16_bf16(onesf.v, pf0_.v, ls, 0, 0, 0);   \
    ls = __builtin_amdgcn_mfma_f32_32x32x16_bf16(onesf.v, pf1_.v, ls, 0, 0, 0);   \
    ls = __builtin_amdgcn_mfma_f32_32x32x16_bf16(onesf.v, pf2_.v, ls, 0, 0, 0);   \
    ls = __builtin_amdgcn_mfma_f32_32x32x16_bf16(onesf.v, pf3_.v, ls, 0, 0, 0);   \
  } while (0)

__global__ __launch_bounds__(64) void attn_k(const u16* __restrict__ Qf,
                                             const u16* __restrict__ Kf,
                                             const u16* __restrict__ Vf,
                                             u16* __restrict__ sc,
                                             u16* __restrict__ pO,
                                             float* __restrict__ pL) {
  const int T = 2048;
  int blk = blockIdx.x;
  int bh = (blk & 7) * 4 + ((blk >> 3) & 3);  // XCD-pinned bh groups
  int c = blk >> 5;                            // 0..79, longest-first
  int qt, slot, nslots;
  if (c < 32) { qt = 63 - (c >> 1); slot = c & 1; nslots = 2; }  // qt 48..63
  else        { qt = 79 - c;        slot = 0;     nslots = 1; }  // qt 0..47
  int nTot = (qt >> 1) + 1;                    // 64-row KV bodies
  int it0 = (nTot * slot) / nslots;
  int itEnd = (nTot * (slot + 1)) / nslots;
  int lane = threadIdx.x & 63;
  int ql = lane & 31, hi = lane >> 5;
  int ln8 = lane * 8;
  int qg = qt * 32 + ql;
  const u16* QfP = Qf + (size_t)bh * 64 * 2048;
  const u16* KfP = Kf + (size_t)bh * 32 * 4096;
  const u16* VfP = Vf + (size_t)bh * 32 * 4096;
  int b = bh >> 4, h = bh & 15;

  U8 onesf;
#pragma unroll
  for (int j = 0; j < 4; j++) onesf.u[j] = 0x3F803F80u;

  bf16x8 qfr[4];
#pragma unroll
  for (int ds = 0; ds < 4; ds++)
    qfr[ds] = *(const bf16x8*)(QfP + (size_t)qt * 2048 + ds * 512 + ln8);

  f32x16 o0 = {}, o1 = {}, ls = {};
  bf16x8 Ka0[4], Ka1[4], Kb0[4], Kb1[4], vv0[4], vv1[4];
  f32x16 sA0, sA1, sB0, sB1;

  int t = it0;
  KPREF(Ka0, Ka1, t);
  QKC(sA0, sA1, Ka0, Ka1);
  if (t + 1 < itEnd) KPREF(Kb0, Kb1, t + 1);

  for (;;) {
    bool last = (t == itEnd - 1);
    VLOADM(t);
    if (t + 2 < itEnd) KPREF(Ka0, Ka1, t + 2);
    if (!last) QKC(sB0, sB1, Kb0, Kb1);
    SMPV(sA0, sA1, t, t == nTot - 1);
    if (last) break;
    ++t;
    last = (t == itEnd - 1);
    VLOADM(t);
    if (t + 2 < itEnd) KPREF(Kb0, Kb1, t + 2);
    if (!last) QKC(sA0, sA1, Ka0, Ka1);
    SMPV(sB0, sB1, t, t == nTot - 1);
    if (last) break;
    ++t;
  }

  if (nslots == 1) {
    float inv = 1.f / ls[0];
    u16* orow = sc + ((size_t)(b * T + qg)) * 1024 + h * 64;
#pragma unroll
    for (int j = 0; j < 4; j++) {
      ushort4 o;
      o.x = f2bf(o0[4 * j + 0] * inv); o.y = f2bf(o0[4 * j + 1] * inv);
      o.z = f2bf(o0[4 * j + 2] * inv); o.w = f2bf(o0[4 * j + 3] * inv);
      *(ushort4*)(orow + 8 * j + 4 * hi) = o;
      ushort4 q2;
      q2.x = f2bf(o1[4 * j + 0] * inv); q2.y = f2bf(o1[4 * j + 1] * inv);
      q2.z = f2bf(o1[4 * j + 2] * inv); q2.w = f2bf(o1[4 * j + 3] * inv);
      *(ushort4*)(orow + 32 + 8 * j + 4 * hi) = q2;
    }
  } else {
    u16* orow = pO + (size_t)slot * 4194304 + ((size_t)(b * T + qg)) * 1024 + h * 64;
#pragma unroll
    for (int j = 0; j < 4; j++) {
      ushort4 o;
      o.x = f2bf(o0[4 * j + 0]); o.y = f2bf(o0[4 * j + 1]);
      o.z = f2bf(o0[4 * j + 2]); o.w = f2bf(o0[4 * j + 3]);
      *(ushort4*)(orow + 8 * j + 4 * hi) = o;
      ushort4 q2;
      q2.x = f2bf(o1[4 * j + 0]); q2.y = f2bf(o1[4 * j + 1]);
      q2.z = f2bf(o1[4 * j + 2]); q2.w = f2bf(o1[4 * j + 3]);
      *(ushort4*)(orow + 32 + 8 * j + 4 * hi) = q2;
    }
    if (hi == 0) pL[slot * 65536 + bh * 2048 + qg] = ls[0];
  }
}

// ---------------- merge partials (rows t >= 1536 only): sc = (O0+O1)/(l0+l1) ----------------
__global__ __launch_bounds__(256) void mrg_k(const u16* __restrict__ pO,
                                             const float* __restrict__ pL,
                                             u16* __restrict__ sc) {
  int id = blockIdx.x * 256 + threadIdx.x;   // 131072 = 2b x 512t x 128 col8
  int col8 = id & 127;
  int rp = id >> 7;                           // 0..1023
  int b = rp >> 9;
  int t = 1536 + (rp & 511);
  int h = col8 >> 3;
  int bh = b * 16 + h;
  size_t idx8 = ((size_t)(b * 2048 + t) * 128 + col8);
  float l0 = pL[bh * 2048 + t];
  float l1 = pL[65536 + bh * 2048 + t];
  u16x8 v0 = *(const u16x8*)(pO + idx8 * 8);
  u16x8 v1 = *(const u16x8*)(pO + 4194304 + idx8 * 8);
  float inv = 1.f / (l0 + l1);
  u16x8 o;
#pragma unroll
  for (int j = 0; j < 8; j++) o[j] = f2bf((bf2f(v0[j]) + bf2f(v1[j])) * inv);
  *(u16x8*)(sc + idx8 * 8) = o;
}

extern "C" void kernel_launch(void* const* d_in, const int* in_sizes, int n_in,
                              void* d_out, int out_size, void* d_ws, size_t ws_size,
                              hipStream_t stream) {
  const float* x      = (const float*)d_in[0];
  const float* W_qkv  = (const float*)d_in[1];
  const float* b_qkv  = (const float*)d_in[2];
  const float* W_proj = (const float*)d_in[3];
  const float* b_proj = (const float*)d_in[4];
  float* out = (float*)d_out;

  const int B = 2, T = 2048, C = 1024;
  const int M = B * T;  // 4096

  // ws map (MB). Partials overlay xb/wqkvt (dead during attn):
  // [0,2) wprojt | [2,10) xb | [10,16) wqkvt | [16,40) qkvb
  // pO = [2,18) (2 x 8MB slots) | pL = [34,35)
  // [40,48) qfb | [48,56) kfb | [56,64) vfb | [64,72) sc
  char* ws = (char*)d_ws;
  u16* wprojt = (u16*)(ws);
  u16* xb     = (u16*)(ws + (2ull << 20));
  u16* wqkvt  = (u16*)(ws + (10ull << 20));
  u16* qkvb   = (u16*)(ws + (16ull << 20));
  u16* pO     = (u16*)(ws + (2ull << 20));
  float* pL   = (float*)(ws + (34ull << 20));
  u16* qfb    = (u16*)(ws + (40ull << 20));
  u16* kfb    = (u16*)(ws + (48ull << 20));
  u16* vfb    = (u16*)(ws + (56ull << 20));
  u16* sc     = (u16*)(ws + (64ull << 20));

  prep_k<<<6144, 256, 0, stream>>>(x, xb, W_qkv, W_proj, wqkvt, wprojt);
  gemm_bt_k<true><<<dim3(3 * C / 128, M / 128), 256, 0, stream>>>(xb, wqkvt, b_qkv, qkvb, M, 3 * C, C);
  rope_pack_k<<<dim3(B * 16, T / 64), 256, 0, stream>>>(qkvb, qfb, kfb, vfb);
  attn_k<<<2560, 64, 0, stream>>>(qfb, kfb, vfb, sc, pO, pL);
  mrg_k<<<512, 256, 0, stream>>>(pO, pL, sc);
  gemm_bt_k<false><<<dim3(C / 128, M / 128), 256, 0, stream>>>(sc, wprojt, b_proj, out, M, C, C);
}